// Round 11
// baseline (271.052 us; speedup 1.0000x reference)
//
#include <hip/hip_runtime.h>

#define N_PTS 16384
#define NH 16
#define NC 192
#define NK 43
#define ND 2
#define BN_EPS 1e-5f
#define NB 16                    // stat-accumulator banks (atomic contention divider)
#define STSTRIDE (NB * 384)      // floats per stat accumulator region

typedef __attribute__((ext_vector_type(8))) short bf16x8;
typedef __attribute__((ext_vector_type(4))) float f32x4;

static __device__ __forceinline__ short f2bf(float f) {
    union { float f; unsigned u; } x; x.f = f;
    unsigned r = x.u + (0x7fffu + ((x.u >> 16) & 1u));   // RNE
    return (short)(r >> 16);
}
static __device__ __forceinline__ float bf2f(short s) {
    union { unsigned u; float f; } x; x.u = ((unsigned)(unsigned short)s) << 16;
    return x.f;
}

// Sum the NB banks of a stat accumulator for channel c (and c+192 for sumsq).
static __device__ __forceinline__ void bank_sum(const float* __restrict__ acc, int c,
                                                float& s, float& q) {
    s = 0.f; q = 0.f;
#pragma unroll
    for (int k = 0; k < NB; ++k) {
        s += acc[k * 384 + c];
        q += acc[k * 384 + 192 + c];
    }
}

// ---------- weight shuffle to MFMA B-frag layout (+ zero stat accumulators) ----------
// Frag element (nt, ks, lane, j) = W[k = ks*32 + (lane>>4)*8 + j][n = nt*16 + (lane&15)]
// Per-layer region: W1b[36864] | Wkb[12288] | W3b[36864] (shorts), stride 86016.
__global__ __launch_bounds__(64) void k_wfrag(const float* __restrict__ W1,
                                              const float* __restrict__ Wk,
                                              const float* __restrict__ W3,
                                              short* __restrict__ Wb,
                                              float* __restrict__ stacc) {
    // zero the 6 banked BN accumulators (atomic targets; re-zeroed every launch
    // so graph replays never see stale sums)
    for (int z = blockIdx.x * 64 + threadIdx.x; z < 6 * STSTRIDE; z += 336 * 64)
        stacc[z] = 0.f;

    int b = blockIdx.x;
    int d = b / 168, r = b % 168;
    const float* src; short* dst; int kb, Ks, tile;
    if (r < 72)      { src = W1 + d * NC * NC; dst = Wb + d * 86016;         kb = 6; Ks = NC; tile = r; }
    else if (r < 96) { src = Wk + d * NK * NC; dst = Wb + d * 86016 + 36864; kb = 2; Ks = NK; tile = r - 72; }
    else             { src = W3 + d * NC * NC; dst = Wb + d * 86016 + 49152; kb = 6; Ks = NC; tile = r - 96; }
    int nt = tile / kb, ks = tile % kb;
    int lane = threadIdx.x, quad = lane >> 4, cl = lane & 15;
    bf16x8 vv;
#pragma unroll
    for (int j = 0; j < 8; ++j) {
        int k = ks * 32 + quad * 8 + j;
        vv[j] = (k < Ks) ? f2bf(src[k * NC + nt * 16 + cl]) : (short)0;
    }
    *(bf16x8*)(dst + ((nt * kb + ks) * 64 + lane) * 8) = vv;
}

// ---------- GEMM1: T(bf16) = A @ W1; A = feat (L0) or relu(feat + bn3_L0(T2)) (L1) ----------
// 1024 blocks x 256 thr; block = 16 rows, wave = one col-quarter (16 rows x 48 cols).
// (exact r7 form, measured in the 218.5us config)
__global__ __launch_bounds__(256, 4) void k_gemm1(const float* __restrict__ feat,
                                                  const short* __restrict__ T2prev,
                                                  const float* __restrict__ st3acc,   // L0 bn3 banked sums (L1 only)
                                                  const float* __restrict__ g3,
                                                  const float* __restrict__ b3,
                                                  short* __restrict__ X1,
                                                  const short* __restrict__ W1b,
                                                  short* __restrict__ T,
                                                  float* __restrict__ st1acc) {
    __shared__ float pa_s[192], ps_s[192];
    const int tid = threadIdx.x;
    const int cq = tid >> 6, lane = tid & 63;       // wave = col-quarter
    const int quad = lane >> 4, cl = lane & 15;
    const int r0 = blockIdx.x * 16;
    const int row = r0 + cl;

    if (T2prev) {   // finalize bn3 of layer 0 into LDS
        if (tid < 192) {
            float s, q; bank_sum(st3acc, tid, s, q);
            float m = s * (1.f / N_PTS);
            float v = q * (1.f / N_PTS) - m * m;
            float a = rsqrtf(v + BN_EPS) * g3[tid];
            pa_s[tid] = a;
            ps_s[tid] = b3[tid] - m * a;
        }
        __syncthreads();
    }

    // ---- hoist the full A-side: 6 ks-steps x 8 floats, loads issue together
    float4 fa[6][2];
    bf16x8 t2v[6];
#pragma unroll
    for (int ks = 0; ks < 6; ++ks) {
        const float* ap = feat + row * NC + ks * 32 + quad * 8;
        fa[ks][0] = *(const float4*)ap;
        fa[ks][1] = *(const float4*)(ap + 4);
    }
    if (T2prev) {
#pragma unroll
        for (int ks = 0; ks < 6; ++ks)
            t2v[ks] = *(const bf16x8*)(T2prev + row * NC + ks * 32 + quad * 8);
    }

    f32x4 acc[3];
#pragma unroll
    for (int nt = 0; nt < 3; ++nt) acc[nt] = (f32x4){0.f, 0.f, 0.f, 0.f};

#pragma unroll
    for (int ks = 0; ks < 6; ++ks) {
        const int k0 = ks * 32 + quad * 8;
        float x[8] = {fa[ks][0].x, fa[ks][0].y, fa[ks][0].z, fa[ks][0].w,
                      fa[ks][1].x, fa[ks][1].y, fa[ks][1].z, fa[ks][1].w};
        if (T2prev) {   // fused skip: x = relu(feat + bn3_L0(T2)); store X1 (bf16)
#pragma unroll
            for (int j = 0; j < 8; ++j)
                x[j] = fmaxf(x[j] + fmaf(pa_s[k0 + j], bf2f(t2v[ks][j]), ps_s[k0 + j]), 0.f);
        }
        bf16x8 af;
#pragma unroll
        for (int j = 0; j < 8; ++j) af[j] = f2bf(x[j]);
        if (T2prev && cq == 0) *(bf16x8*)(X1 + row * NC + k0) = af;   // store once per row
#pragma unroll
        for (int nt = 0; nt < 3; ++nt) {
            const int ntg = cq * 3 + nt;
            bf16x8 bf = *(const bf16x8*)(W1b + ((ntg * 6 + ks) * 64 + lane) * 8);
            acc[nt] = __builtin_amdgcn_mfma_f32_16x16x32_bf16(af, bf, acc[nt], 0, 0, 0);
        }
    }
#pragma unroll
    for (int nt = 0; nt < 3; ++nt) {
        int c = (cq * 3 + nt) * 16 + cl;
        float s = 0.f, sq = 0.f;
#pragma unroll
        for (int r = 0; r < 4; ++r) {
            float v = acc[nt][r];
            T[(r0 + quad * 4 + r) * NC + c] = f2bf(v);
            s += v; sq = fmaf(v, v, sq);
        }
        s += __shfl_xor(s, 16); s += __shfl_xor(s, 32);
        sq += __shfl_xor(sq, 16); sq += __shfl_xor(sq, 32);
        if (quad == 0) {   // banked: 1024 blocks / 16 banks = 64 RMW per address
            float* dst = st1acc + (blockIdx.x & (NB - 1)) * 384;
            atomicAdd(&dst[c], s);
            atomicAdd(&dst[192 + c], sq);
        }
    }
}

// ---------- kpconv: U = sum_h (infl @ Wk)[h,c] * relu(bn1(T[ref[h]]))[h,c] ----------
// 2048 blocks x 512 thr; 8 waves = 8 points per block, ONE point per wave.
// r11 change: NO Wk LDS staging. Wkb (24.6 KB, identical for all 2048 blocks) is
// L2-resident broadcast data — read B-frags directly from global, like the GEMMs
// already do with W1b/W3b. This deletes the 3-pass staging loop and shrinks the
// pre-compute barrier to the 192-thread BN-finalize; the 24 B-frag loads join the
// 48 gathers as independent outstanding L2 loads (more MLP). LDS 39.4 -> 14.8 KB.
__global__ __launch_bounds__(512) void k_kpconv(const float* __restrict__ coord,
                                                const int* __restrict__ ridx,
                                                const float* __restrict__ kp,
                                                const short* __restrict__ Wkb,
                                                const short* __restrict__ T,
                                                const float* __restrict__ st1acc,
                                                const float* __restrict__ g1,
                                                const float* __restrict__ b1,
                                                short* __restrict__ U,
                                                float* __restrict__ st2acc) {
    __shared__ __align__(16) float4 kp_s[64];
    __shared__ float a1s[192], s1s[192];
    __shared__ float red[8][384];

    const int tid = threadIdx.x;
    const int wave = tid >> 6, lane = tid & 63;
    const int quad = lane >> 4, cl = lane & 15;
    const int n = blockIdx.x * 8 + wave;

    // ---- phase 0 (pre-barrier): per-point dependent chain, ~8 VGPRs live ----
    int idh = 0; float nbx = 0.f, nby = 0.f, nbz = 0.f;
    if (lane < NH) {
        idh = ridx[n * NH + lane];
        float cx = coord[n * 3 + 0], cy = coord[n * 3 + 1], cz = coord[n * 3 + 2];
        nbx = coord[idh * 3 + 0] - cx;
        nby = coord[idh * 3 + 1] - cy;
        nbz = coord[idh * 3 + 2] - cz;
    }
    const float nx = __shfl(nbx, cl), ny = __shfl(nby, cl), nz = __shfl(nbz, cl);
    int rowb[4];
#pragma unroll
    for (int r = 0; r < 4; ++r) rowb[r] = __shfl(idh, quad * 4 + r) * NC;

    // ---- phase 1: small LDS staging (kp_s + bn1 finalize) + barrier ----
    {
        if (tid < 64) {
            bool ok = tid < NK;
            float x = ok ? kp[tid * 3 + 0] : 1e9f;
            float y = ok ? kp[tid * 3 + 1] : 1e9f;
            float z = ok ? kp[tid * 3 + 2] : 1e9f;
            kp_s[tid] = (float4){x, y, z, fmaf(x, x, fmaf(y, y, z * z))};
        }
        if (tid < 192) {   // finalize bn1 from banked sums
            float s, q; bank_sum(st1acc, tid, s, q);
            float m = s * (1.f / N_PTS);
            float v = q * (1.f / N_PTS) - m * m;
            float a = rsqrtf(v + BN_EPS) * g1[tid];
            a1s[tid] = a;
            s1s[tid] = b1[tid] - m * a;
        }
    }
    __syncthreads();

    // ---- phase 2: hoisted gather (48 loads issued before influence+MFMA) ----
    unsigned short xv[12][4];
    const unsigned short* Tu = (const unsigned short*)T;
#pragma unroll
    for (int nt = 0; nt < 12; ++nt)
#pragma unroll
        for (int r = 0; r < 4; ++r)
            xv[nt][r] = Tu[rowb[r] + nt * 16 + cl];

    // ---- influence A-fragments: d^2 = |nb|^2 + |kp|^2 - 2 nb.kp
    const float nb2 = fmaf(nx, nx, fmaf(ny, ny, nz * nz));
    const float m2x = -2.f * nx, m2y = -2.f * ny, m2z = -2.f * nz;
    bf16x8 af[2];
#pragma unroll
    for (int ks = 0; ks < 2; ++ks) {
#pragma unroll
        for (int j = 0; j < 8; ++j) {
            int k = ks * 32 + quad * 8 + j;
            float4 kpv = kp_s[k];
            float t = nb2 + kpv.w;
            t = fmaf(m2x, kpv.x, t);
            t = fmaf(m2y, kpv.y, t);
            t = fmaf(m2z, kpv.z, t);
            float d = sqrtf(fmaxf(t, 0.f));
            af[ks][j] = f2bf(fmaxf(1.f - d, 0.f));   // SIGMA = 1; pads -> 0
        }
    }

    // ---- A = infl @ Wk via MFMA; B-frags read directly from global (L2-hot) ----
    f32x4 acc[12];
#pragma unroll
    for (int nt = 0; nt < 12; ++nt) {
        bf16x8 b0 = *(const bf16x8*)(Wkb + ((nt * 2 + 0) * 64 + lane) * 8);
        bf16x8 b1v = *(const bf16x8*)(Wkb + ((nt * 2 + 1) * 64 + lane) * 8);
        f32x4 z = (f32x4){0.f, 0.f, 0.f, 0.f};
        z = __builtin_amdgcn_mfma_f32_16x16x32_bf16(af[0], b0, z, 0, 0, 0);
        acc[nt] = __builtin_amdgcn_mfma_f32_16x16x32_bf16(af[1], b1v, z, 0, 0, 0);
    }

    // ---- aggregate: U[n,c] = sum_h acc[h,c] * relu(bn1(xv[h,c])); keep BN2 partials
#pragma unroll
    for (int nt = 0; nt < 12; ++nt) {
        const float a1c = a1s[nt * 16 + cl], s1c = s1s[nt * 16 + cl];
        float u = 0.f;
#pragma unroll
        for (int r = 0; r < 4; ++r) {
            float t = bf2f((short)xv[nt][r]);
            float x = fmaxf(fmaf(a1c, t, s1c), 0.f);
            u = fmaf(acc[nt][r], x, u);
        }
        u += __shfl_xor(u, 16);
        u += __shfl_xor(u, 32);
        if (quad == 0) {
            U[n * NC + nt * 16 + cl] = f2bf(u);
            red[wave][nt * 16 + cl] = u;
            red[wave][192 + nt * 16 + cl] = u * u;
        }
    }

    // ---- per-block reduce of BN2 partial sums, one banked atomic per channel
    __syncthreads();
    if (tid < 384) {
        float S = 0.f;
#pragma unroll
        for (int w = 0; w < 8; ++w) S += red[w][tid];
        atomicAdd(&st2acc[(blockIdx.x & (NB - 1)) * 384 + tid], S);
    }
}

// ---------- GEMM3: T2(bf16) = relu(bn2(U)) @ W3 ----------
// Same col-quarter split as gemm1 (exact r7 form from the 218.5us config).
__global__ __launch_bounds__(256, 4) void k_gemm3(const short* __restrict__ U,
                                                  const float* __restrict__ st2acc,
                                                  const float* __restrict__ g2,
                                                  const float* __restrict__ b2,
                                                  const short* __restrict__ W3b,
                                                  short* __restrict__ T2,
                                                  float* __restrict__ st3acc) {
    __shared__ float a2s[192], s2s[192];
    const int tid = threadIdx.x;
    const int cq = tid >> 6, lane = tid & 63;
    const int quad = lane >> 4, cl = lane & 15;
    const int r0 = blockIdx.x * 16;
    const int row = r0 + cl;

    if (tid < 192) {   // finalize bn2 from banked sums
        float s, q; bank_sum(st2acc, tid, s, q);
        float m = s * (1.f / N_PTS);
        float v = q * (1.f / N_PTS) - m * m;
        float a = rsqrtf(v + BN_EPS) * g2[tid];
        a2s[tid] = a;
        s2s[tid] = b2[tid] - m * a;
    }
    __syncthreads();

    // ---- hoist the full A-side: 6 x bf16x8
    bf16x8 u8v[6];
#pragma unroll
    for (int ks = 0; ks < 6; ++ks)
        u8v[ks] = *(const bf16x8*)(U + row * NC + ks * 32 + quad * 8);

    f32x4 acc[3];
#pragma unroll
    for (int nt = 0; nt < 3; ++nt) acc[nt] = (f32x4){0.f, 0.f, 0.f, 0.f};

#pragma unroll
    for (int ks = 0; ks < 6; ++ks) {
        const int k0 = ks * 32 + quad * 8;
        bf16x8 af;
#pragma unroll
        for (int j = 0; j < 8; ++j)
            af[j] = f2bf(fmaxf(fmaf(a2s[k0 + j], bf2f(u8v[ks][j]), s2s[k0 + j]), 0.f));
#pragma unroll
        for (int nt = 0; nt < 3; ++nt) {
            const int ntg = cq * 3 + nt;
            bf16x8 bf = *(const bf16x8*)(W3b + ((ntg * 6 + ks) * 64 + lane) * 8);
            acc[nt] = __builtin_amdgcn_mfma_f32_16x16x32_bf16(af, bf, acc[nt], 0, 0, 0);
        }
    }
#pragma unroll
    for (int nt = 0; nt < 3; ++nt) {
        int c = (cq * 3 + nt) * 16 + cl;
        float s = 0.f, sq = 0.f;
#pragma unroll
        for (int r = 0; r < 4; ++r) {
            float v = acc[nt][r];
            T2[(r0 + quad * 4 + r) * NC + c] = f2bf(v);
            s += v; sq = fmaf(v, v, sq);
        }
        s += __shfl_xor(s, 16); s += __shfl_xor(s, 32);
        sq += __shfl_xor(sq, 16); sq += __shfl_xor(sq, 32);
        if (quad == 0) {
            float* dst = st3acc + (blockIdx.x & (NB - 1)) * 384;
            atomicAdd(&dst[c], s);
            atomicAdd(&dst[192 + c], sq);
        }
    }
}

// ---------- final: out = relu(X1 + bn3_L1(T2)); bn3 finalized in prologue ----------
__global__ __launch_bounds__(256) void k_final(const short* __restrict__ T2,
                                               const float* __restrict__ st3acc,
                                               const float* __restrict__ g3,
                                               const float* __restrict__ b3,
                                               const short* __restrict__ X1,
                                               float* __restrict__ out) {
    __shared__ float a3s[192], s3s[192];
    if (threadIdx.x < 192) {
        float s, q; bank_sum(st3acc, threadIdx.x, s, q);
        float m = s * (1.f / N_PTS);
        float v = q * (1.f / N_PTS) - m * m;
        float a = rsqrtf(v + BN_EPS) * g3[threadIdx.x];
        a3s[threadIdx.x] = a;
        s3s[threadIdx.x] = b3[threadIdx.x] - m * a;
    }
    __syncthreads();

    const int i = blockIdx.x * 256 + threadIdx.x;   // grid covers N*NC/8 exactly
    const int c0 = (i * 8) % 192;
    bf16x8 t2 = *(const bf16x8*)(T2 + (long)i * 8);
    bf16x8 x1 = *(const bf16x8*)(X1 + (long)i * 8);
    float o[8];
#pragma unroll
    for (int j = 0; j < 8; ++j)
        o[j] = fmaxf(bf2f(x1[j]) + fmaf(a3s[c0 + j], bf2f(t2[j]), s3s[c0 + j]), 0.f);
    *(float4*)(out + (long)i * 8)     = (float4){o[0], o[1], o[2], o[3]};
    *(float4*)(out + (long)i * 8 + 4) = (float4){o[4], o[5], o[6], o[7]};
}

extern "C" void kernel_launch(void* const* d_in, const int* in_sizes, int n_in,
                              void* d_out, int out_size, void* d_ws, size_t ws_size,
                              hipStream_t stream) {
    const float* coord = (const float*)d_in[0];
    const float* feat  = (const float*)d_in[1];
    const int*   ridx  = (const int*)d_in[2];
    const float* kp    = (const float*)d_in[3];
    const float* W1    = (const float*)d_in[4];
    const float* Wk    = (const float*)d_in[5];
    const float* W3    = (const float*)d_in[6];
    const float* g1    = (const float*)d_in[7];
    const float* b1    = (const float*)d_in[8];
    const float* g2    = (const float*)d_in[9];
    const float* b2    = (const float*)d_in[10];
    const float* g3    = (const float*)d_in[11];
    const float* b3    = (const float*)d_in[12];
    float* out = (float*)d_out;

    // ws (floats): stacc[6*STSTRIDE banked] | shorts: X1 | T | U | T2 | Wb
    float* stacc = (float*)d_ws;
    short* X1 = (short*)(stacc + 6 * STSTRIDE);
    short* T  = X1 + N_PTS * NC;
    short* U  = T + N_PTS * NC;
    short* T2 = U + N_PTS * NC;
    short* Wb = T2 + N_PTS * NC;

    k_wfrag<<<336, 64, 0, stream>>>(W1, Wk, W3, Wb, stacc);

    for (int d = 0; d < ND; ++d) {
        const short* W1b = Wb + d * 86016;
        const short* Wkb = W1b + 36864;
        const short* W3b = W1b + 49152;
        float* st1acc = stacc + (d * 3 + 0) * STSTRIDE;
        float* st2acc = stacc + (d * 3 + 1) * STSTRIDE;
        float* st3acc = stacc + (d * 3 + 2) * STSTRIDE;

        k_gemm1<<<N_PTS / 16, 256, 0, stream>>>(feat,
                                                d ? T2 : (short*)nullptr,
                                                stacc + 2 * STSTRIDE,   // bn3 banked sums of layer 0
                                                g3, b3,                 // layer-0 slices
                                                X1, W1b, T, st1acc);
        k_kpconv<<<N_PTS / 8, 512, 0, stream>>>(coord, ridx, kp, Wkb, T,
                                                st1acc, g1 + d * NC, b1 + d * NC,
                                                U, st2acc);
        k_gemm3<<<N_PTS / 16, 256, 0, stream>>>(U, st2acc, g2 + d * NC, b2 + d * NC,
                                                W3b, T2, st3acc);
    }
    k_final<<<N_PTS * NC / 8 / 256, 256, 0, stream>>>(T2, stacc + 5 * STSTRIDE,
                                                      g3 + NC, b3 + NC, X1, out);
}

// Round 13
// 234.271 us; speedup vs baseline: 1.1570x; 1.1570x over previous
//
#include <hip/hip_runtime.h>

#define N_PTS 16384
#define NH 16
#define NC 192
#define NK 43
#define ND 2
#define BN_EPS 1e-5f
#define NB 16                    // stat-accumulator banks (atomic contention divider)
#define STSTRIDE (NB * 384)      // floats per stat accumulator region

typedef __attribute__((ext_vector_type(8))) short bf16x8;
typedef __attribute__((ext_vector_type(4))) float f32x4;

static __device__ __forceinline__ short f2bf(float f) {
    union { float f; unsigned u; } x; x.f = f;
    unsigned r = x.u + (0x7fffu + ((x.u >> 16) & 1u));   // RNE
    return (short)(r >> 16);
}
static __device__ __forceinline__ float bf2f(short s) {
    union { unsigned u; float f; } x; x.u = ((unsigned)(unsigned short)s) << 16;
    return x.f;
}

// Sum the NB banks of a stat accumulator for channel c (and c+192 for sumsq).
static __device__ __forceinline__ void bank_sum(const float* __restrict__ acc, int c,
                                                float& s, float& q) {
    s = 0.f; q = 0.f;
#pragma unroll
    for (int k = 0; k < NB; ++k) {
        s += acc[k * 384 + c];
        q += acc[k * 384 + 192 + c];
    }
}

// ---------- weight shuffle to MFMA B-frag layout (+ zero stat accumulators) ----------
// Frag element (nt, ks, lane, j) = W[k = ks*32 + (lane>>4)*8 + j][n = nt*16 + (lane&15)]
// Per-layer region: W1b[36864] | Wkb[12288] | W3b[36864] (shorts), stride 86016.
__global__ __launch_bounds__(64) void k_wfrag(const float* __restrict__ W1,
                                              const float* __restrict__ Wk,
                                              const float* __restrict__ W3,
                                              short* __restrict__ Wb,
                                              float* __restrict__ stacc) {
    // zero the 6 banked BN accumulators (atomic targets; re-zeroed every launch
    // so graph replays never see stale sums)
    for (int z = blockIdx.x * 64 + threadIdx.x; z < 6 * STSTRIDE; z += 336 * 64)
        stacc[z] = 0.f;

    int b = blockIdx.x;
    int d = b / 168, r = b % 168;
    const float* src; short* dst; int kb, Ks, tile;
    if (r < 72)      { src = W1 + d * NC * NC; dst = Wb + d * 86016;         kb = 6; Ks = NC; tile = r; }
    else if (r < 96) { src = Wk + d * NK * NC; dst = Wb + d * 86016 + 36864; kb = 2; Ks = NK; tile = r - 72; }
    else             { src = W3 + d * NC * NC; dst = Wb + d * 86016 + 49152; kb = 6; Ks = NC; tile = r - 96; }
    int nt = tile / kb, ks = tile % kb;
    int lane = threadIdx.x, quad = lane >> 4, cl = lane & 15;
    bf16x8 vv;
#pragma unroll
    for (int j = 0; j < 8; ++j) {
        int k = ks * 32 + quad * 8 + j;
        vv[j] = (k < Ks) ? f2bf(src[k * NC + nt * 16 + cl]) : (short)0;
    }
    *(bf16x8*)(dst + ((nt * kb + ks) * 64 + lane) * 8) = vv;
}

// ---------- GEMM1: T(bf16) = A @ W1; A = feat (L0) or relu(feat + bn3_L0(T2)) (L1) ----------
// 1024 blocks x 256 thr; block = 16 rows, wave = one col-quarter (16 rows x 48 cols).
// (exact r7 form, measured in the 218.5us config)
__global__ __launch_bounds__(256, 4) void k_gemm1(const float* __restrict__ feat,
                                                  const short* __restrict__ T2prev,
                                                  const float* __restrict__ st3acc,   // L0 bn3 banked sums (L1 only)
                                                  const float* __restrict__ g3,
                                                  const float* __restrict__ b3,
                                                  short* __restrict__ X1,
                                                  const short* __restrict__ W1b,
                                                  short* __restrict__ T,
                                                  float* __restrict__ st1acc) {
    __shared__ float pa_s[192], ps_s[192];
    const int tid = threadIdx.x;
    const int cq = tid >> 6, lane = tid & 63;       // wave = col-quarter
    const int quad = lane >> 4, cl = lane & 15;
    const int r0 = blockIdx.x * 16;
    const int row = r0 + cl;

    if (T2prev) {   // finalize bn3 of layer 0 into LDS
        if (tid < 192) {
            float s, q; bank_sum(st3acc, tid, s, q);
            float m = s * (1.f / N_PTS);
            float v = q * (1.f / N_PTS) - m * m;
            float a = rsqrtf(v + BN_EPS) * g3[tid];
            pa_s[tid] = a;
            ps_s[tid] = b3[tid] - m * a;
        }
        __syncthreads();
    }

    // ---- hoist the full A-side: 6 ks-steps x 8 floats, loads issue together
    float4 fa[6][2];
    bf16x8 t2v[6];
#pragma unroll
    for (int ks = 0; ks < 6; ++ks) {
        const float* ap = feat + row * NC + ks * 32 + quad * 8;
        fa[ks][0] = *(const float4*)ap;
        fa[ks][1] = *(const float4*)(ap + 4);
    }
    if (T2prev) {
#pragma unroll
        for (int ks = 0; ks < 6; ++ks)
            t2v[ks] = *(const bf16x8*)(T2prev + row * NC + ks * 32 + quad * 8);
    }

    f32x4 acc[3];
#pragma unroll
    for (int nt = 0; nt < 3; ++nt) acc[nt] = (f32x4){0.f, 0.f, 0.f, 0.f};

#pragma unroll
    for (int ks = 0; ks < 6; ++ks) {
        const int k0 = ks * 32 + quad * 8;
        float x[8] = {fa[ks][0].x, fa[ks][0].y, fa[ks][0].z, fa[ks][0].w,
                      fa[ks][1].x, fa[ks][1].y, fa[ks][1].z, fa[ks][1].w};
        if (T2prev) {   // fused skip: x = relu(feat + bn3_L0(T2)); store X1 (bf16)
#pragma unroll
            for (int j = 0; j < 8; ++j)
                x[j] = fmaxf(x[j] + fmaf(pa_s[k0 + j], bf2f(t2v[ks][j]), ps_s[k0 + j]), 0.f);
        }
        bf16x8 af;
#pragma unroll
        for (int j = 0; j < 8; ++j) af[j] = f2bf(x[j]);
        if (T2prev && cq == 0) *(bf16x8*)(X1 + row * NC + k0) = af;   // store once per row
#pragma unroll
        for (int nt = 0; nt < 3; ++nt) {
            const int ntg = cq * 3 + nt;
            bf16x8 bf = *(const bf16x8*)(W1b + ((ntg * 6 + ks) * 64 + lane) * 8);
            acc[nt] = __builtin_amdgcn_mfma_f32_16x16x32_bf16(af, bf, acc[nt], 0, 0, 0);
        }
    }
#pragma unroll
    for (int nt = 0; nt < 3; ++nt) {
        int c = (cq * 3 + nt) * 16 + cl;
        float s = 0.f, sq = 0.f;
#pragma unroll
        for (int r = 0; r < 4; ++r) {
            float v = acc[nt][r];
            T[(r0 + quad * 4 + r) * NC + c] = f2bf(v);
            s += v; sq = fmaf(v, v, sq);
        }
        s += __shfl_xor(s, 16); s += __shfl_xor(s, 32);
        sq += __shfl_xor(sq, 16); sq += __shfl_xor(sq, 32);
        if (quad == 0) {   // banked: 1024 blocks / 16 banks = 64 RMW per address
            float* dst = st1acc + (blockIdx.x & (NB - 1)) * 384;
            atomicAdd(&dst[c], s);
            atomicAdd(&dst[192 + c], sq);
        }
    }
}

// ---------- kpconv: U = sum_h (infl @ Wk)[h,c] * relu(bn1(T[ref[h]]))[h,c] ----------
// r13 = r12 with the BN2 epilogue fixed for 256-thread blocks (r12's `if(tid<384)`
// silently dropped sumsq channels 64..191 -> absmax 12 failure).
// 4096 blocks x 256 thr; 4 waves = 4 points per block, ONE point per wave
// (per-wave code = measured-best r9/r10 form; Wk LDS staging kept, r11 proved
// it's worth ~23us/dispatch). Finer granularity: 16 blocks/CU of work, ~4
// co-resident (33KB LDS) -> smoother refill/drain, target 4 waves/SIMD.
__global__ __launch_bounds__(256) void k_kpconv(const float* __restrict__ coord,
                                                const int* __restrict__ ridx,
                                                const float* __restrict__ kp,
                                                const short* __restrict__ Wkb,
                                                const short* __restrict__ T,
                                                const float* __restrict__ st1acc,
                                                const float* __restrict__ g1,
                                                const float* __restrict__ b1,
                                                short* __restrict__ U,
                                                float* __restrict__ st2acc) {
    __shared__ __align__(16) short wk_s[12288];     // 24576 B Wk B-frags
    __shared__ __align__(16) float4 kp_s[64];       // 1024 B
    __shared__ float a1s[192], s1s[192];            // 1536 B
    __shared__ float red[4][384];                   // 6144 B

    const int tid = threadIdx.x;
    const int wave = tid >> 6, lane = tid & 63;
    const int quad = lane >> 4, cl = lane & 15;
    const int n = blockIdx.x * 4 + wave;

    // ---- phase 0 (pre-staging): per-point dependent chain, ~8 VGPRs live ----
    int idh = 0; float nbx = 0.f, nby = 0.f, nbz = 0.f;
    if (lane < NH) {
        idh = ridx[n * NH + lane];
        float cx = coord[n * 3 + 0], cy = coord[n * 3 + 1], cz = coord[n * 3 + 2];
        nbx = coord[idh * 3 + 0] - cx;
        nby = coord[idh * 3 + 1] - cy;
        nbz = coord[idh * 3 + 2] - cz;
    }
    const float nx = __shfl(nbx, cl), ny = __shfl(nby, cl), nz = __shfl(nbz, cl);
    int rowb[4];
#pragma unroll
    for (int r = 0; r < 4; ++r) rowb[r] = __shfl(idh, quad * 4 + r) * NC;

    // ---- phase 1: LDS staging (wk_s + kp_s + bn1 finalize) + barrier ----
    {
        const float4* src = (const float4*)Wkb;
        float4* dst = (float4*)wk_s;
        for (int j = tid; j < 1536; j += 256) dst[j] = src[j];
        if (tid < 64) {
            bool ok = tid < NK;
            float x = ok ? kp[tid * 3 + 0] : 1e9f;
            float y = ok ? kp[tid * 3 + 1] : 1e9f;
            float z = ok ? kp[tid * 3 + 2] : 1e9f;
            kp_s[tid] = (float4){x, y, z, fmaf(x, x, fmaf(y, y, z * z))};
        }
        if (tid < 192) {   // finalize bn1 from banked sums
            float s, q; bank_sum(st1acc, tid, s, q);
            float m = s * (1.f / N_PTS);
            float v = q * (1.f / N_PTS) - m * m;
            float a = rsqrtf(v + BN_EPS) * g1[tid];
            a1s[tid] = a;
            s1s[tid] = b1[tid] - m * a;
        }
    }
    __syncthreads();

    // ---- phase 2: hoisted gather (48 loads issued before influence+MFMA) ----
    unsigned short xv[12][4];
    const unsigned short* Tu = (const unsigned short*)T;
#pragma unroll
    for (int nt = 0; nt < 12; ++nt)
#pragma unroll
        for (int r = 0; r < 4; ++r)
            xv[nt][r] = Tu[rowb[r] + nt * 16 + cl];

    // ---- influence A-fragments: d^2 = |nb|^2 + |kp|^2 - 2 nb.kp
    const float nb2 = fmaf(nx, nx, fmaf(ny, ny, nz * nz));
    const float m2x = -2.f * nx, m2y = -2.f * ny, m2z = -2.f * nz;
    bf16x8 af[2];
#pragma unroll
    for (int ks = 0; ks < 2; ++ks) {
#pragma unroll
        for (int j = 0; j < 8; ++j) {
            int k = ks * 32 + quad * 8 + j;
            float4 kpv = kp_s[k];
            float t = nb2 + kpv.w;
            t = fmaf(m2x, kpv.x, t);
            t = fmaf(m2y, kpv.y, t);
            t = fmaf(m2z, kpv.z, t);
            float d = sqrtf(fmaxf(t, 0.f));
            af[ks][j] = f2bf(fmaxf(1.f - d, 0.f));   // SIGMA = 1; pads -> 0
        }
    }

    // ---- A = infl @ Wk via MFMA (12 n-tiles x 2 k-steps), B-frags from LDS
    f32x4 acc[12];
#pragma unroll
    for (int nt = 0; nt < 12; ++nt) {
        bf16x8 b0 = *(const bf16x8*)(wk_s + ((nt * 2 + 0) * 64 + lane) * 8);
        bf16x8 b1v = *(const bf16x8*)(wk_s + ((nt * 2 + 1) * 64 + lane) * 8);
        f32x4 z = (f32x4){0.f, 0.f, 0.f, 0.f};
        z = __builtin_amdgcn_mfma_f32_16x16x32_bf16(af[0], b0, z, 0, 0, 0);
        acc[nt] = __builtin_amdgcn_mfma_f32_16x16x32_bf16(af[1], b1v, z, 0, 0, 0);
    }

    // ---- aggregate: U[n,c] = sum_h acc[h,c] * relu(bn1(xv[h,c])); keep BN2 partials
#pragma unroll
    for (int nt = 0; nt < 12; ++nt) {
        const float a1c = a1s[nt * 16 + cl], s1c = s1s[nt * 16 + cl];
        float u = 0.f;
#pragma unroll
        for (int r = 0; r < 4; ++r) {
            float t = bf2f((short)xv[nt][r]);
            float x = fmaxf(fmaf(a1c, t, s1c), 0.f);
            u = fmaf(acc[nt][r], x, u);
        }
        u += __shfl_xor(u, 16);
        u += __shfl_xor(u, 32);
        if (quad == 0) {
            U[n * NC + nt * 16 + cl] = f2bf(u);
            red[wave][nt * 16 + cl] = u;
            red[wave][192 + nt * 16 + cl] = u * u;
        }
    }

    // ---- per-block reduce of BN2 partial sums, one banked atomic per channel
    // (grid-stride over all 384 channels — 256-thread block covers them in 2 passes)
    __syncthreads();
    for (int t = tid; t < 384; t += 256) {
        float S = 0.f;
#pragma unroll
        for (int w = 0; w < 4; ++w) S += red[w][t];
        atomicAdd(&st2acc[(blockIdx.x & (NB - 1)) * 384 + t], S);
    }
}

// ---------- GEMM3: T2(bf16) = relu(bn2(U)) @ W3 ----------
// Same col-quarter split as gemm1 (exact r7 form from the 218.5us config).
__global__ __launch_bounds__(256, 4) void k_gemm3(const short* __restrict__ U,
                                                  const float* __restrict__ st2acc,
                                                  const float* __restrict__ g2,
                                                  const float* __restrict__ b2,
                                                  const short* __restrict__ W3b,
                                                  short* __restrict__ T2,
                                                  float* __restrict__ st3acc) {
    __shared__ float a2s[192], s2s[192];
    const int tid = threadIdx.x;
    const int cq = tid >> 6, lane = tid & 63;
    const int quad = lane >> 4, cl = lane & 15;
    const int r0 = blockIdx.x * 16;
    const int row = r0 + cl;

    if (tid < 192) {   // finalize bn2 from banked sums
        float s, q; bank_sum(st2acc, tid, s, q);
        float m = s * (1.f / N_PTS);
        float v = q * (1.f / N_PTS) - m * m;
        float a = rsqrtf(v + BN_EPS) * g2[tid];
        a2s[tid] = a;
        s2s[tid] = b2[tid] - m * a;
    }
    __syncthreads();

    // ---- hoist the full A-side: 6 x bf16x8
    bf16x8 u8v[6];
#pragma unroll
    for (int ks = 0; ks < 6; ++ks)
        u8v[ks] = *(const bf16x8*)(U + row * NC + ks * 32 + quad * 8);

    f32x4 acc[3];
#pragma unroll
    for (int nt = 0; nt < 3; ++nt) acc[nt] = (f32x4){0.f, 0.f, 0.f, 0.f};

#pragma unroll
    for (int ks = 0; ks < 6; ++ks) {
        const int k0 = ks * 32 + quad * 8;
        bf16x8 af;
#pragma unroll
        for (int j = 0; j < 8; ++j)
            af[j] = f2bf(fmaxf(fmaf(a2s[k0 + j], bf2f(u8v[ks][j]), s2s[k0 + j]), 0.f));
#pragma unroll
        for (int nt = 0; nt < 3; ++nt) {
            const int ntg = cq * 3 + nt;
            bf16x8 bf = *(const bf16x8*)(W3b + ((ntg * 6 + ks) * 64 + lane) * 8);
            acc[nt] = __builtin_amdgcn_mfma_f32_16x16x32_bf16(af, bf, acc[nt], 0, 0, 0);
        }
    }
#pragma unroll
    for (int nt = 0; nt < 3; ++nt) {
        int c = (cq * 3 + nt) * 16 + cl;
        float s = 0.f, sq = 0.f;
#pragma unroll
        for (int r = 0; r < 4; ++r) {
            float v = acc[nt][r];
            T2[(r0 + quad * 4 + r) * NC + c] = f2bf(v);
            s += v; sq = fmaf(v, v, sq);
        }
        s += __shfl_xor(s, 16); s += __shfl_xor(s, 32);
        sq += __shfl_xor(sq, 16); sq += __shfl_xor(sq, 32);
        if (quad == 0) {
            float* dst = st3acc + (blockIdx.x & (NB - 1)) * 384;
            atomicAdd(&dst[c], s);
            atomicAdd(&dst[192 + c], sq);
        }
    }
}

// ---------- final: out = relu(X1 + bn3_L1(T2)); bn3 finalized in prologue ----------
__global__ __launch_bounds__(256) void k_final(const short* __restrict__ T2,
                                               const float* __restrict__ st3acc,
                                               const float* __restrict__ g3,
                                               const float* __restrict__ b3,
                                               const short* __restrict__ X1,
                                               float* __restrict__ out) {
    __shared__ float a3s[192], s3s[192];
    if (threadIdx.x < 192) {
        float s, q; bank_sum(st3acc, threadIdx.x, s, q);
        float m = s * (1.f / N_PTS);
        float v = q * (1.f / N_PTS) - m * m;
        float a = rsqrtf(v + BN_EPS) * g3[threadIdx.x];
        a3s[threadIdx.x] = a;
        s3s[threadIdx.x] = b3[threadIdx.x] - m * a;
    }
    __syncthreads();

    const int i = blockIdx.x * 256 + threadIdx.x;   // grid covers N*NC/8 exactly
    const int c0 = (i * 8) % 192;
    bf16x8 t2 = *(const bf16x8*)(T2 + (long)i * 8);
    bf16x8 x1 = *(const bf16x8*)(X1 + (long)i * 8);
    float o[8];
#pragma unroll
    for (int j = 0; j < 8; ++j)
        o[j] = fmaxf(bf2f(x1[j]) + fmaf(a3s[c0 + j], bf2f(t2[j]), s3s[c0 + j]), 0.f);
    *(float4*)(out + (long)i * 8)     = (float4){o[0], o[1], o[2], o[3]};
    *(float4*)(out + (long)i * 8 + 4) = (float4){o[4], o[5], o[6], o[7]};
}

extern "C" void kernel_launch(void* const* d_in, const int* in_sizes, int n_in,
                              void* d_out, int out_size, void* d_ws, size_t ws_size,
                              hipStream_t stream) {
    const float* coord = (const float*)d_in[0];
    const float* feat  = (const float*)d_in[1];
    const int*   ridx  = (const int*)d_in[2];
    const float* kp    = (const float*)d_in[3];
    const float* W1    = (const float*)d_in[4];
    const float* Wk    = (const float*)d_in[5];
    const float* W3    = (const float*)d_in[6];
    const float* g1    = (const float*)d_in[7];
    const float* b1    = (const float*)d_in[8];
    const float* g2    = (const float*)d_in[9];
    const float* b2    = (const float*)d_in[10];
    const float* g3    = (const float*)d_in[11];
    const float* b3    = (const float*)d_in[12];
    float* out = (float*)d_out;

    // ws (floats): stacc[6*STSTRIDE banked] | shorts: X1 | T | U | T2 | Wb
    float* stacc = (float*)d_ws;
    short* X1 = (short*)(stacc + 6 * STSTRIDE);
    short* T  = X1 + N_PTS * NC;
    short* U  = T + N_PTS * NC;
    short* T2 = U + N_PTS * NC;
    short* Wb = T2 + N_PTS * NC;

    k_wfrag<<<336, 64, 0, stream>>>(W1, Wk, W3, Wb, stacc);

    for (int d = 0; d < ND; ++d) {
        const short* W1b = Wb + d * 86016;
        const short* Wkb = W1b + 36864;
        const short* W3b = W1b + 49152;
        float* st1acc = stacc + (d * 3 + 0) * STSTRIDE;
        float* st2acc = stacc + (d * 3 + 1) * STSTRIDE;
        float* st3acc = stacc + (d * 3 + 2) * STSTRIDE;

        k_gemm1<<<N_PTS / 16, 256, 0, stream>>>(feat,
                                                d ? T2 : (short*)nullptr,
                                                stacc + 2 * STSTRIDE,   // bn3 banked sums of layer 0
                                                g3, b3,                 // layer-0 slices
                                                X1, W1b, T, st1acc);
        k_kpconv<<<N_PTS / 4, 256, 0, stream>>>(coord, ridx, kp, Wkb, T,
                                                st1acc, g1 + d * NC, b1 + d * NC,
                                                U, st2acc);
        k_gemm3<<<N_PTS / 16, 256, 0, stream>>>(U, st2acc, g2 + d * NC, b2 + d * NC,
                                                W3b, T2, st3acc);
    }
    k_final<<<N_PTS * NC / 8 / 256, 256, 0, stream>>>(T2, stacc + 5 * STSTRIDE,
                                                      g3 + NC, b3 + NC, X1, out);
}

// Round 14
// 214.638 us; speedup vs baseline: 1.2628x; 1.0915x over previous
//
#include <hip/hip_runtime.h>

#define N_PTS 16384
#define NH 16
#define NC 192
#define NK 43
#define ND 2
#define BN_EPS 1e-5f
#define NB 16                    // stat-accumulator banks (atomic contention divider)
#define STSTRIDE (NB * 384)      // floats per stat accumulator region
#define RS 196                   // padded LDS row stride (shorts): bank-spread for u16 reads

typedef __attribute__((ext_vector_type(8))) short bf16x8;
typedef __attribute__((ext_vector_type(4))) short bf16x4;
typedef __attribute__((ext_vector_type(4))) float f32x4;

static __device__ __forceinline__ short f2bf(float f) {
    union { float f; unsigned u; } x; x.f = f;
    unsigned r = x.u + (0x7fffu + ((x.u >> 16) & 1u));   // RNE
    return (short)(r >> 16);
}
static __device__ __forceinline__ float bf2f(short s) {
    union { unsigned u; float f; } x; x.u = ((unsigned)(unsigned short)s) << 16;
    return x.f;
}

// Sum the NB banks of a stat accumulator for channel c (and c+192 for sumsq).
static __device__ __forceinline__ void bank_sum(const float* __restrict__ acc, int c,
                                                float& s, float& q) {
    s = 0.f; q = 0.f;
#pragma unroll
    for (int k = 0; k < NB; ++k) {
        s += acc[k * 384 + c];
        q += acc[k * 384 + 192 + c];
    }
}

// ---------- weight shuffle to MFMA B-frag layout (+ zero stat accumulators) ----------
// Frag element (nt, ks, lane, j) = W[k = ks*32 + (lane>>4)*8 + j][n = nt*16 + (lane&15)]
// Per-layer region: W1b[36864] | Wkb[12288] | W3b[36864] (shorts), stride 86016.
__global__ __launch_bounds__(64) void k_wfrag(const float* __restrict__ W1,
                                              const float* __restrict__ Wk,
                                              const float* __restrict__ W3,
                                              short* __restrict__ Wb,
                                              float* __restrict__ stacc) {
    // zero the 6 banked BN accumulators (atomic targets; re-zeroed every launch
    // so graph replays never see stale sums)
    for (int z = blockIdx.x * 64 + threadIdx.x; z < 6 * STSTRIDE; z += 336 * 64)
        stacc[z] = 0.f;

    int b = blockIdx.x;
    int d = b / 168, r = b % 168;
    const float* src; short* dst; int kb, Ks, tile;
    if (r < 72)      { src = W1 + d * NC * NC; dst = Wb + d * 86016;         kb = 6; Ks = NC; tile = r; }
    else if (r < 96) { src = Wk + d * NK * NC; dst = Wb + d * 86016 + 36864; kb = 2; Ks = NK; tile = r - 72; }
    else             { src = W3 + d * NC * NC; dst = Wb + d * 86016 + 49152; kb = 6; Ks = NC; tile = r - 96; }
    int nt = tile / kb, ks = tile % kb;
    int lane = threadIdx.x, quad = lane >> 4, cl = lane & 15;
    bf16x8 vv;
#pragma unroll
    for (int j = 0; j < 8; ++j) {
        int k = ks * 32 + quad * 8 + j;
        vv[j] = (k < Ks) ? f2bf(src[k * NC + nt * 16 + cl]) : (short)0;
    }
    *(bf16x8*)(dst + ((nt * kb + ks) * 64 + lane) * 8) = vv;
}

// ---------- GEMM1: T(bf16) = A @ W1; A = feat (L0) or relu(feat + bn3_L0(T2)) (L1) ----------
// 1024 blocks x 256 thr; block = 16 rows, wave = one col-quarter (16 rows x 48 cols).
// (exact r7 form, measured in the 218.5us config)
__global__ __launch_bounds__(256, 4) void k_gemm1(const float* __restrict__ feat,
                                                  const short* __restrict__ T2prev,
                                                  const float* __restrict__ st3acc,   // L0 bn3 banked sums (L1 only)
                                                  const float* __restrict__ g3,
                                                  const float* __restrict__ b3,
                                                  short* __restrict__ X1,
                                                  const short* __restrict__ W1b,
                                                  short* __restrict__ T,
                                                  float* __restrict__ st1acc) {
    __shared__ float pa_s[192], ps_s[192];
    const int tid = threadIdx.x;
    const int cq = tid >> 6, lane = tid & 63;       // wave = col-quarter
    const int quad = lane >> 4, cl = lane & 15;
    const int r0 = blockIdx.x * 16;
    const int row = r0 + cl;

    if (T2prev) {   // finalize bn3 of layer 0 into LDS
        if (tid < 192) {
            float s, q; bank_sum(st3acc, tid, s, q);
            float m = s * (1.f / N_PTS);
            float v = q * (1.f / N_PTS) - m * m;
            float a = rsqrtf(v + BN_EPS) * g3[tid];
            pa_s[tid] = a;
            ps_s[tid] = b3[tid] - m * a;
        }
        __syncthreads();
    }

    // ---- hoist the full A-side: 6 ks-steps x 8 floats, loads issue together
    float4 fa[6][2];
    bf16x8 t2v[6];
#pragma unroll
    for (int ks = 0; ks < 6; ++ks) {
        const float* ap = feat + row * NC + ks * 32 + quad * 8;
        fa[ks][0] = *(const float4*)ap;
        fa[ks][1] = *(const float4*)(ap + 4);
    }
    if (T2prev) {
#pragma unroll
        for (int ks = 0; ks < 6; ++ks)
            t2v[ks] = *(const bf16x8*)(T2prev + row * NC + ks * 32 + quad * 8);
    }

    f32x4 acc[3];
#pragma unroll
    for (int nt = 0; nt < 3; ++nt) acc[nt] = (f32x4){0.f, 0.f, 0.f, 0.f};

#pragma unroll
    for (int ks = 0; ks < 6; ++ks) {
        const int k0 = ks * 32 + quad * 8;
        float x[8] = {fa[ks][0].x, fa[ks][0].y, fa[ks][0].z, fa[ks][0].w,
                      fa[ks][1].x, fa[ks][1].y, fa[ks][1].z, fa[ks][1].w};
        if (T2prev) {   // fused skip: x = relu(feat + bn3_L0(T2)); store X1 (bf16)
#pragma unroll
            for (int j = 0; j < 8; ++j)
                x[j] = fmaxf(x[j] + fmaf(pa_s[k0 + j], bf2f(t2v[ks][j]), ps_s[k0 + j]), 0.f);
        }
        bf16x8 af;
#pragma unroll
        for (int j = 0; j < 8; ++j) af[j] = f2bf(x[j]);
        if (T2prev && cq == 0) *(bf16x8*)(X1 + row * NC + k0) = af;   // store once per row
#pragma unroll
        for (int nt = 0; nt < 3; ++nt) {
            const int ntg = cq * 3 + nt;
            bf16x8 bf = *(const bf16x8*)(W1b + ((ntg * 6 + ks) * 64 + lane) * 8);
            acc[nt] = __builtin_amdgcn_mfma_f32_16x16x32_bf16(af, bf, acc[nt], 0, 0, 0);
        }
    }
#pragma unroll
    for (int nt = 0; nt < 3; ++nt) {
        int c = (cq * 3 + nt) * 16 + cl;
        float s = 0.f, sq = 0.f;
#pragma unroll
        for (int r = 0; r < 4; ++r) {
            float v = acc[nt][r];
            T[(r0 + quad * 4 + r) * NC + c] = f2bf(v);
            s += v; sq = fmaf(v, v, sq);
        }
        s += __shfl_xor(s, 16); s += __shfl_xor(s, 32);
        sq += __shfl_xor(sq, 16); sq += __shfl_xor(sq, 32);
        if (quad == 0) {   // banked: 1024 blocks / 16 banks = 64 RMW per address
            float* dst = st1acc + (blockIdx.x & (NB - 1)) * 384;
            atomicAdd(&dst[c], s);
            atomicAdd(&dst[192 + c], sq);
        }
    }
}

// ---------- kpconv: U = sum_h (infl @ Wk)[h,c] * relu(bn1(T[ref[h]]))[h,c] ----------
// 2048 blocks x 512 thr; 8 waves = 8 points per block, ONE point per wave.
// r10 measured-best form (216.9us total): 48 scalar u16 gathers replaced by 6
// vectorized bf16x8 row loads (full neighbor rows, coalesced) staged into a
// per-wave LDS row buffer (stride RS=196 shorts: consumption reads 2 lanes/bank,
// conflict-free). The BN2 red buffer aliases the row buffer after consumption
// (u[] kept in regs), LDS = 77.3 KB. No live state crosses a barrier.
__global__ __launch_bounds__(512) void k_kpconv(const float* __restrict__ coord,
                                                const int* __restrict__ ridx,
                                                const float* __restrict__ kp,
                                                const short* __restrict__ Wkb,
                                                const short* __restrict__ T,
                                                const float* __restrict__ st1acc,
                                                const float* __restrict__ g1,
                                                const float* __restrict__ b1,
                                                short* __restrict__ U,
                                                float* __restrict__ st2acc) {
    __shared__ __align__(16) short wk_s[12288];        // 24576 B Wk B-frags
    __shared__ __align__(16) float4 kp_s[64];          // 1024 B
    __shared__ float a1s[192], s1s[192];               // 1536 B
    __shared__ __align__(16) short rows_s[8][16 * RS]; // 50176 B; per-wave 16 gathered rows
                                                       // (aliased as BN2 red[384] after use)

    const int tid = threadIdx.x;
    const int wave = tid >> 6, lane = tid & 63;
    const int quad = lane >> 4, cl = lane & 15;
    const int n = blockIdx.x * 8 + wave;

    // ---- phase 0 (pre-staging): per-point dependent chain, ~8 VGPRs live ----
    int idh = 0; float nbx = 0.f, nby = 0.f, nbz = 0.f;
    if (lane < NH) {
        idh = ridx[n * NH + lane];
        float cx = coord[n * 3 + 0], cy = coord[n * 3 + 1], cz = coord[n * 3 + 2];
        nbx = coord[idh * 3 + 0] - cx;
        nby = coord[idh * 3 + 1] - cy;
        nbz = coord[idh * 3 + 2] - cz;
    }
    const float nx = __shfl(nbx, cl), ny = __shfl(nby, cl), nz = __shfl(nbz, cl);

    // ---- phase 1: LDS staging (wk_s + kp_s + bn1 finalize) + barrier ----
    {
        const float4* src = (const float4*)Wkb;
        float4* dst = (float4*)wk_s;
        for (int j = tid; j < 1536; j += 512) dst[j] = src[j];
        if (tid < 64) {
            bool ok = tid < NK;
            float x = ok ? kp[tid * 3 + 0] : 1e9f;
            float y = ok ? kp[tid * 3 + 1] : 1e9f;
            float z = ok ? kp[tid * 3 + 2] : 1e9f;
            kp_s[tid] = (float4){x, y, z, fmaf(x, x, fmaf(y, y, z * z))};
        }
        if (tid < 192) {   // finalize bn1 from banked sums
            float s, q; bank_sum(st1acc, tid, s, q);
            float m = s * (1.f / N_PTS);
            float v = q * (1.f / N_PTS) - m * m;
            float a = rsqrtf(v + BN_EPS) * g1[tid];
            a1s[tid] = a;
            s1s[tid] = b1[tid] - m * a;
        }
    }
    __syncthreads();

    // ---- phase 2: vectorized row gather: 6 x bf16x8 per lane covers 16 rows x 192ch
    // (chunk id = j*64+lane -> row id/24, 16B-chunk id%24; row base via shfl)
    bf16x8 gv[6];
    const short* Ts = T;
#pragma unroll
    for (int j = 0; j < 6; ++j) {
        int id = j * 64 + lane;
        int r = id / 24, c8 = id - r * 24;
        int rb = __shfl(idh, r) * NC;
        gv[j] = *(const bf16x8*)(Ts + rb + c8 * 8);
    }

    // ---- influence A-fragments (VALU; overlaps gather latency) ----
    const float nb2 = fmaf(nx, nx, fmaf(ny, ny, nz * nz));
    const float m2x = -2.f * nx, m2y = -2.f * ny, m2z = -2.f * nz;
    bf16x8 af[2];
#pragma unroll
    for (int ks = 0; ks < 2; ++ks) {
#pragma unroll
        for (int j = 0; j < 8; ++j) {
            int k = ks * 32 + quad * 8 + j;
            float4 kpv = kp_s[k];
            float t = nb2 + kpv.w;
            t = fmaf(m2x, kpv.x, t);
            t = fmaf(m2y, kpv.y, t);
            t = fmaf(m2z, kpv.z, t);
            float d = sqrtf(fmaxf(t, 0.f));
            af[ks][j] = f2bf(fmaxf(1.f - d, 0.f));   // SIGMA = 1; pads -> 0
        }
    }

    // ---- spill gathered rows to this wave's LDS row buffer (8B-aligned b64 writes)
#pragma unroll
    for (int j = 0; j < 6; ++j) {
        int id = j * 64 + lane;
        int r = id / 24, c8 = id - r * 24;
        short* dp = &rows_s[wave][r * RS + c8 * 8];
        *(bf16x4*)dp       = (bf16x4){gv[j][0], gv[j][1], gv[j][2], gv[j][3]};
        *(bf16x4*)(dp + 4) = (bf16x4){gv[j][4], gv[j][5], gv[j][6], gv[j][7]};
    }

    // ---- A = infl @ Wk via MFMA (12 n-tiles x 2 k-steps), B-frags from LDS
    f32x4 acc[12];
#pragma unroll
    for (int nt = 0; nt < 12; ++nt) {
        bf16x8 b0 = *(const bf16x8*)(wk_s + ((nt * 2 + 0) * 64 + lane) * 8);
        bf16x8 b1v = *(const bf16x8*)(wk_s + ((nt * 2 + 1) * 64 + lane) * 8);
        f32x4 z = (f32x4){0.f, 0.f, 0.f, 0.f};
        z = __builtin_amdgcn_mfma_f32_16x16x32_bf16(af[0], b0, z, 0, 0, 0);
        acc[nt] = __builtin_amdgcn_mfma_f32_16x16x32_bf16(af[1], b1v, z, 0, 0, 0);
    }

    // ---- aggregate: U[n,c] = sum_h acc[h,c] * relu(bn1(rows[h,c])); u[] kept in regs
    float u[12];
#pragma unroll
    for (int nt = 0; nt < 12; ++nt) {
        const float a1c = a1s[nt * 16 + cl], s1c = s1s[nt * 16 + cl];
        float uu = 0.f;
#pragma unroll
        for (int r = 0; r < 4; ++r) {
            float t = bf2f(rows_s[wave][(quad * 4 + r) * RS + nt * 16 + cl]);
            float x = fmaxf(fmaf(a1c, t, s1c), 0.f);
            uu = fmaf(acc[nt][r], x, uu);
        }
        uu += __shfl_xor(uu, 16);
        uu += __shfl_xor(uu, 32);
        u[nt] = uu;
        if (quad == 0) U[n * NC + nt * 16 + cl] = f2bf(uu);
    }

    // ---- rows_s[wave] fully consumed: alias it as this wave's red[384]
    {
        float* red_w = (float*)&rows_s[wave][0];
        if (quad == 0) {
#pragma unroll
            for (int nt = 0; nt < 12; ++nt) {
                red_w[nt * 16 + cl] = u[nt];
                red_w[192 + nt * 16 + cl] = u[nt] * u[nt];
            }
        }
    }
    __syncthreads();
    if (tid < 384) {
        float S = 0.f;
#pragma unroll
        for (int w = 0; w < 8; ++w) S += ((const float*)&rows_s[w][0])[tid];
        atomicAdd(&st2acc[(blockIdx.x & (NB - 1)) * 384 + tid], S);
    }
}

// ---------- GEMM3: T2(bf16) = relu(bn2(U)) @ W3 ----------
// Same col-quarter split as gemm1 (exact r7 form from the 218.5us config).
__global__ __launch_bounds__(256, 4) void k_gemm3(const short* __restrict__ U,
                                                  const float* __restrict__ st2acc,
                                                  const float* __restrict__ g2,
                                                  const float* __restrict__ b2,
                                                  const short* __restrict__ W3b,
                                                  short* __restrict__ T2,
                                                  float* __restrict__ st3acc) {
    __shared__ float a2s[192], s2s[192];
    const int tid = threadIdx.x;
    const int cq = tid >> 6, lane = tid & 63;
    const int quad = lane >> 4, cl = lane & 15;
    const int r0 = blockIdx.x * 16;
    const int row = r0 + cl;

    if (tid < 192) {   // finalize bn2 from banked sums
        float s, q; bank_sum(st2acc, tid, s, q);
        float m = s * (1.f / N_PTS);
        float v = q * (1.f / N_PTS) - m * m;
        float a = rsqrtf(v + BN_EPS) * g2[tid];
        a2s[tid] = a;
        s2s[tid] = b2[tid] - m * a;
    }
    __syncthreads();

    // ---- hoist the full A-side: 6 x bf16x8
    bf16x8 u8v[6];
#pragma unroll
    for (int ks = 0; ks < 6; ++ks)
        u8v[ks] = *(const bf16x8*)(U + row * NC + ks * 32 + quad * 8);

    f32x4 acc[3];
#pragma unroll
    for (int nt = 0; nt < 3; ++nt) acc[nt] = (f32x4){0.f, 0.f, 0.f, 0.f};

#pragma unroll
    for (int ks = 0; ks < 6; ++ks) {
        const int k0 = ks * 32 + quad * 8;
        bf16x8 af;
#pragma unroll
        for (int j = 0; j < 8; ++j)
            af[j] = f2bf(fmaxf(fmaf(a2s[k0 + j], bf2f(u8v[ks][j]), s2s[k0 + j]), 0.f));
#pragma unroll
        for (int nt = 0; nt < 3; ++nt) {
            const int ntg = cq * 3 + nt;
            bf16x8 bf = *(const bf16x8*)(W3b + ((ntg * 6 + ks) * 64 + lane) * 8);
            acc[nt] = __builtin_amdgcn_mfma_f32_16x16x32_bf16(af, bf, acc[nt], 0, 0, 0);
        }
    }
#pragma unroll
    for (int nt = 0; nt < 3; ++nt) {
        int c = (cq * 3 + nt) * 16 + cl;
        float s = 0.f, sq = 0.f;
#pragma unroll
        for (int r = 0; r < 4; ++r) {
            float v = acc[nt][r];
            T2[(r0 + quad * 4 + r) * NC + c] = f2bf(v);
            s += v; sq = fmaf(v, v, sq);
        }
        s += __shfl_xor(s, 16); s += __shfl_xor(s, 32);
        sq += __shfl_xor(sq, 16); sq += __shfl_xor(sq, 32);
        if (quad == 0) {
            float* dst = st3acc + (blockIdx.x & (NB - 1)) * 384;
            atomicAdd(&dst[c], s);
            atomicAdd(&dst[192 + c], sq);
        }
    }
}

// ---------- final: out = relu(X1 + bn3_L1(T2)); bn3 finalized in prologue ----------
__global__ __launch_bounds__(256) void k_final(const short* __restrict__ T2,
                                               const float* __restrict__ st3acc,
                                               const float* __restrict__ g3,
                                               const float* __restrict__ b3,
                                               const short* __restrict__ X1,
                                               float* __restrict__ out) {
    __shared__ float a3s[192], s3s[192];
    if (threadIdx.x < 192) {
        float s, q; bank_sum(st3acc, threadIdx.x, s, q);
        float m = s * (1.f / N_PTS);
        float v = q * (1.f / N_PTS) - m * m;
        float a = rsqrtf(v + BN_EPS) * g3[threadIdx.x];
        a3s[threadIdx.x] = a;
        s3s[threadIdx.x] = b3[threadIdx.x] - m * a;
    }
    __syncthreads();

    const int i = blockIdx.x * 256 + threadIdx.x;   // grid covers N*NC/8 exactly
    const int c0 = (i * 8) % 192;
    bf16x8 t2 = *(const bf16x8*)(T2 + (long)i * 8);
    bf16x8 x1 = *(const bf16x8*)(X1 + (long)i * 8);
    float o[8];
#pragma unroll
    for (int j = 0; j < 8; ++j)
        o[j] = fmaxf(bf2f(x1[j]) + fmaf(a3s[c0 + j], bf2f(t2[j]), s3s[c0 + j]), 0.f);
    *(float4*)(out + (long)i * 8)     = (float4){o[0], o[1], o[2], o[3]};
    *(float4*)(out + (long)i * 8 + 4) = (float4){o[4], o[5], o[6], o[7]};
}

extern "C" void kernel_launch(void* const* d_in, const int* in_sizes, int n_in,
                              void* d_out, int out_size, void* d_ws, size_t ws_size,
                              hipStream_t stream) {
    const float* coord = (const float*)d_in[0];
    const float* feat  = (const float*)d_in[1];
    const int*   ridx  = (const int*)d_in[2];
    const float* kp    = (const float*)d_in[3];
    const float* W1    = (const float*)d_in[4];
    const float* Wk    = (const float*)d_in[5];
    const float* W3    = (const float*)d_in[6];
    const float* g1    = (const float*)d_in[7];
    const float* b1    = (const float*)d_in[8];
    const float* g2    = (const float*)d_in[9];
    const float* b2    = (const float*)d_in[10];
    const float* g3    = (const float*)d_in[11];
    const float* b3    = (const float*)d_in[12];
    float* out = (float*)d_out;

    // ws (floats): stacc[6*STSTRIDE banked] | shorts: X1 | T | U | T2 | Wb
    float* stacc = (float*)d_ws;
    short* X1 = (short*)(stacc + 6 * STSTRIDE);
    short* T  = X1 + N_PTS * NC;
    short* U  = T + N_PTS * NC;
    short* T2 = U + N_PTS * NC;
    short* Wb = T2 + N_PTS * NC;

    k_wfrag<<<336, 64, 0, stream>>>(W1, Wk, W3, Wb, stacc);

    for (int d = 0; d < ND; ++d) {
        const short* W1b = Wb + d * 86016;
        const short* Wkb = W1b + 36864;
        const short* W3b = W1b + 49152;
        float* st1acc = stacc + (d * 3 + 0) * STSTRIDE;
        float* st2acc = stacc + (d * 3 + 1) * STSTRIDE;
        float* st3acc = stacc + (d * 3 + 2) * STSTRIDE;

        k_gemm1<<<N_PTS / 16, 256, 0, stream>>>(feat,
                                                d ? T2 : (short*)nullptr,
                                                stacc + 2 * STSTRIDE,   // bn3 banked sums of layer 0
                                                g3, b3,                 // layer-0 slices
                                                X1, W1b, T, st1acc);
        k_kpconv<<<N_PTS / 8, 512, 0, stream>>>(coord, ridx, kp, Wkb, T,
                                                st1acc, g1 + d * NC, b1 + d * NC,
                                                U, st2acc);
        k_gemm3<<<N_PTS / 16, 256, 0, stream>>>(U, st2acc, g2 + d * NC, b2 + d * NC,
                                                W3b, T2, st3acc);
    }
    k_final<<<N_PTS * NC / 8 / 256, 256, 0, stream>>>(T2, stacc + 5 * STSTRIDE,
                                                      g3 + NC, b3 + NC, X1, out);
}